// Round 1
// baseline (1389.769 us; speedup 1.0000x reference)
//
#include <hip/hip_runtime.h>

#define N_NODES 100000
#define N_CLASS 64          // NUM_CLASS + 1
#define N_EDGES 1600000

// Fused: value = poss_edge * w; atomicAdd into per-node accumulator (in d_out);
// also stream poss_edge straight through to the second output region.
// Layout: 16 threads per edge, each thread owns 4 consecutive classes (float4).
__global__ void scatter_copy_kernel(const int* __restrict__ edges,
                                    const float* __restrict__ weights,
                                    const float* __restrict__ poss_edge,
                                    float* __restrict__ acc,
                                    float* __restrict__ pe_out) {
    const int total = N_EDGES * 16;            // 25.6M work items
    const int stride = gridDim.x * blockDim.x;
    for (int t = blockIdx.x * blockDim.x + threadIdx.x; t < total; t += stride) {
        const int e  = t >> 4;                 // edge index
        const int c0 = (t & 15) << 2;          // class offset 0,4,...,60
        const float4 pe = *reinterpret_cast<const float4*>(poss_edge + (size_t)e * N_CLASS + c0);
        const float  w  = weights[e];
        const int    src = edges[2 * e];       // edges[e][0]

        // pass-through copy (coalesced float4 store)
        *reinterpret_cast<float4*>(pe_out + (size_t)e * N_CLASS + c0) = pe;

        float* a = acc + (size_t)src * N_CLASS + c0;
        atomicAdd(a + 0, pe.x * w);
        atomicAdd(a + 1, pe.y * w);
        atomicAdd(a + 2, pe.z * w);
        atomicAdd(a + 3, pe.w * w);
    }
}

// poss_node /= neighbours_sum (broadcast per node)
__global__ void divide_kernel(float* __restrict__ acc,
                              const float* __restrict__ nsum) {
    const int t = blockIdx.x * blockDim.x + threadIdx.x;
    if (t >= N_NODES * 16) return;
    const int   node = t >> 4;
    const float d    = nsum[node];
    float4 v = *reinterpret_cast<float4*>(acc + (size_t)t * 4);
    v.x /= d; v.y /= d; v.z /= d; v.w /= d;
    *reinterpret_cast<float4*>(acc + (size_t)t * 4) = v;
}

extern "C" void kernel_launch(void* const* d_in, const int* in_sizes, int n_in,
                              void* d_out, int out_size, void* d_ws, size_t ws_size,
                              hipStream_t stream) {
    const int*   edges     = (const int*)d_in[0];
    const float* weights   = (const float*)d_in[1];
    const float* poss_edge = (const float*)d_in[2];
    const float* nsum      = (const float*)d_in[3];

    float* out    = (float*)d_out;
    float* acc    = out;                        // N_NODES * 64 floats
    float* pe_out = out + (size_t)N_NODES * N_CLASS;

    // zero the accumulator region every call (deterministic; memset node is capturable)
    hipMemsetAsync(acc, 0, (size_t)N_NODES * N_CLASS * sizeof(float), stream);

    scatter_copy_kernel<<<8192, 256, 0, stream>>>(edges, weights, poss_edge, acc, pe_out);

    const int div_threads = N_NODES * 16;
    divide_kernel<<<(div_threads + 255) / 256, 256, 0, stream>>>(acc, nsum);
}

// Round 2
// 766.971 us; speedup vs baseline: 1.8120x; 1.8120x over previous
//
#include <hip/hip_runtime.h>

#define N_NODES 100000
#define N_CLASS 64          // NUM_CLASS + 1
#define N_EDGES 1600000

// ---------------- CSR-gather path (no f32 atomics) ----------------
// ws layout: offsets [N_NODES+1] | cursor [N_NODES] | edge_ids [N_EDGES]

__global__ void hist_kernel(const int* __restrict__ edges, int* __restrict__ counts) {
    const int stride = gridDim.x * blockDim.x;
    for (int e = blockIdx.x * blockDim.x + threadIdx.x; e < N_EDGES; e += stride) {
        atomicAdd(&counts[edges[2 * e]], 1);
    }
}

// Single-block exclusive scan over N_NODES counts (in `cursor`), writing
// offsets[] and resetting cursor[] to the exclusive prefix (placement cursors).
__global__ void scan_kernel(int* __restrict__ cursor, int* __restrict__ offsets) {
    const int T = 1024;
    const int t = threadIdx.x;
    const int chunk = (N_NODES + T - 1) / T;          // 98
    const int base  = t * chunk;
    const int end   = min(base + chunk, N_NODES);

    int local = 0;
    for (int i = base; i < end; ++i) local += cursor[i];

    __shared__ int s[T];
    s[t] = local;
    __syncthreads();
    for (int d = 1; d < T; d <<= 1) {
        int v = (t >= d) ? s[t - d] : 0;
        __syncthreads();
        s[t] += v;
        __syncthreads();
    }
    int run = s[t] - local;                           // exclusive prefix of this chunk
    for (int i = base; i < end; ++i) {
        int c = cursor[i];
        offsets[i] = run;
        cursor[i]  = run;
        run += c;
    }
    if (t == T - 1) offsets[N_NODES] = run;           // total = N_EDGES
}

__global__ void place_kernel(const int* __restrict__ edges,
                             int* __restrict__ cursor,
                             int* __restrict__ edge_ids) {
    const int stride = gridDim.x * blockDim.x;
    for (int e = blockIdx.x * blockDim.x + threadIdx.x; e < N_EDGES; e += stride) {
        const int src = edges[2 * e];
        const int pos = atomicAdd(&cursor[src], 1);
        edge_ids[pos] = e;
    }
}

// One wave per node; lane = class. Sums w[e]*pe[e][lane] over the node's
// edges, writes sum/nsum once. Fuses the poss_edge pass-through copy
// (each edge row is loaded exactly once here).
__global__ void gather_kernel(const int* __restrict__ offsets,
                              const int* __restrict__ edge_ids,
                              const float* __restrict__ weights,
                              const float* __restrict__ poss_edge,
                              const float* __restrict__ nsum,
                              float* __restrict__ acc,
                              float* __restrict__ pe_out) {
    const int gtid = blockIdx.x * blockDim.x + threadIdx.x;
    const int node = gtid >> 6;
    const int lane = threadIdx.x & 63;
    if (node >= N_NODES) return;

    const int beg = offsets[node];
    const int end = offsets[node + 1];

    float val = 0.0f;
    for (int j = beg; j < end; ++j) {
        const int   e  = edge_ids[j];
        const float w  = weights[e];
        const float pv = poss_edge[(size_t)e * N_CLASS + lane];
        pe_out[(size_t)e * N_CLASS + lane] = pv;
        val = fmaf(pv, w, val);
    }
    acc[(size_t)node * N_CLASS + lane] = val / nsum[node];
}

// ---------------- fallback (round-1 atomic path) ----------------
__global__ void scatter_copy_kernel(const int* __restrict__ edges,
                                    const float* __restrict__ weights,
                                    const float* __restrict__ poss_edge,
                                    float* __restrict__ acc,
                                    float* __restrict__ pe_out) {
    const int total = N_EDGES * 16;
    const int stride = gridDim.x * blockDim.x;
    for (int t = blockIdx.x * blockDim.x + threadIdx.x; t < total; t += stride) {
        const int e  = t >> 4;
        const int c0 = (t & 15) << 2;
        const float4 pe = *reinterpret_cast<const float4*>(poss_edge + (size_t)e * N_CLASS + c0);
        const float  w  = weights[e];
        const int    src = edges[2 * e];
        *reinterpret_cast<float4*>(pe_out + (size_t)e * N_CLASS + c0) = pe;
        float* a = acc + (size_t)src * N_CLASS + c0;
        atomicAdd(a + 0, pe.x * w);
        atomicAdd(a + 1, pe.y * w);
        atomicAdd(a + 2, pe.z * w);
        atomicAdd(a + 3, pe.w * w);
    }
}

__global__ void divide_kernel(float* __restrict__ acc,
                              const float* __restrict__ nsum) {
    const int t = blockIdx.x * blockDim.x + threadIdx.x;
    if (t >= N_NODES * 16) return;
    const int   node = t >> 4;
    const float d    = nsum[node];
    float4 v = *reinterpret_cast<float4*>(acc + (size_t)t * 4);
    v.x /= d; v.y /= d; v.z /= d; v.w /= d;
    *reinterpret_cast<float4*>(acc + (size_t)t * 4) = v;
}

extern "C" void kernel_launch(void* const* d_in, const int* in_sizes, int n_in,
                              void* d_out, int out_size, void* d_ws, size_t ws_size,
                              hipStream_t stream) {
    const int*   edges     = (const int*)d_in[0];
    const float* weights   = (const float*)d_in[1];
    const float* poss_edge = (const float*)d_in[2];
    const float* nsum      = (const float*)d_in[3];

    float* out    = (float*)d_out;
    float* acc    = out;                                  // N_NODES*64 floats
    float* pe_out = out + (size_t)N_NODES * N_CLASS;

    const size_t ws_needed = (size_t)(N_NODES + 1 + N_NODES + N_EDGES) * sizeof(int);

    if (ws_size >= ws_needed) {
        int* offsets  = (int*)d_ws;                       // N_NODES+1
        int* cursor   = offsets + (N_NODES + 1);          // N_NODES
        int* edge_ids = cursor + N_NODES;                 // N_EDGES

        hipMemsetAsync(cursor, 0, (size_t)N_NODES * sizeof(int), stream);
        hist_kernel <<<2048, 256, 0, stream>>>(edges, cursor);
        scan_kernel <<<1, 1024, 0, stream>>>(cursor, offsets);
        place_kernel<<<2048, 256, 0, stream>>>(edges, cursor, edge_ids);

        const int threads = N_NODES * 64;                 // one wave per node
        gather_kernel<<<(threads + 255) / 256, 256, 0, stream>>>(
            offsets, edge_ids, weights, poss_edge, nsum, acc, pe_out);
    } else {
        hipMemsetAsync(acc, 0, (size_t)N_NODES * N_CLASS * sizeof(float), stream);
        scatter_copy_kernel<<<8192, 256, 0, stream>>>(edges, weights, poss_edge, acc, pe_out);
        const int div_threads = N_NODES * 16;
        divide_kernel<<<(div_threads + 255) / 256, 256, 0, stream>>>(acc, nsum);
    }
}

// Round 3
// 399.758 us; speedup vs baseline: 3.4765x; 1.9186x over previous
//
#include <hip/hip_runtime.h>

#define N_NODES 100000
#define N_CLASS 64          // NUM_CLASS + 1
#define N_EDGES 1600000
#define SCAN_NB 200         // 200 blocks * 512 elems = 102400 >= N_NODES
#define SCAN_T  256

// ws layout: offsets [N_NODES+1] | cursor [N_NODES] | bsum [256] | edge_ids [N_EDGES]
// hist accumulates counts directly into offsets[0..N-1]; scan converts in-place.

__global__ void hist_kernel(const int* __restrict__ edges, int* __restrict__ counts) {
    const int stride = gridDim.x * blockDim.x;
    const int2* e2 = (const int2*)edges;
    for (int e = blockIdx.x * blockDim.x + threadIdx.x; e < N_EDGES; e += stride) {
        atomicAdd(&counts[e2[e].x], 1);
    }
}

// Phase A: per-block sums of 512-count tiles
__global__ void scanA_kernel(const int* __restrict__ counts, int* __restrict__ bsum) {
    __shared__ int s[SCAN_T];
    const int b = blockIdx.x, t = threadIdx.x;
    const int i0 = b * 512 + 2 * t;
    int c0 = (i0     < N_NODES) ? counts[i0]     : 0;
    int c1 = (i0 + 1 < N_NODES) ? counts[i0 + 1] : 0;
    s[t] = c0 + c1;
    __syncthreads();
    for (int d = SCAN_T / 2; d > 0; d >>= 1) {
        if (t < d) s[t] += s[t + d];
        __syncthreads();
    }
    if (t == 0) bsum[b] = s[0];
}

// Phase B: exclusive scan of the 200 block sums (single tiny block)
__global__ void scanB_kernel(int* __restrict__ bsum, int* __restrict__ offsets) {
    __shared__ int s[SCAN_T];
    const int t = threadIdx.x;
    const int v = (t < SCAN_NB) ? bsum[t] : 0;
    s[t] = v;
    __syncthreads();
    for (int d = 1; d < SCAN_T; d <<= 1) {
        int x = (t >= d) ? s[t - d] : 0;
        __syncthreads();
        s[t] += x;
        __syncthreads();
    }
    if (t < SCAN_NB) bsum[t] = s[t] - v;              // exclusive
    if (t == SCAN_T - 1) offsets[N_NODES] = s[t];     // total = N_EDGES
}

// Phase C: local exclusive scan per tile + block offset; writes offsets & cursor.
// Reads counts from `offsets` (in-place: each thread reads its elems before writing).
__global__ void scanC_kernel(int* __restrict__ offsets, const int* __restrict__ bsum,
                             int* __restrict__ cursor) {
    __shared__ int s[SCAN_T];
    const int b = blockIdx.x, t = threadIdx.x;
    const int i0 = b * 512 + 2 * t;
    int c0 = (i0     < N_NODES) ? offsets[i0]     : 0;
    int c1 = (i0 + 1 < N_NODES) ? offsets[i0 + 1] : 0;
    const int pair = c0 + c1;
    s[t] = pair;
    __syncthreads();
    for (int d = 1; d < SCAN_T; d <<= 1) {
        int x = (t >= d) ? s[t - d] : 0;
        __syncthreads();
        s[t] += x;
        __syncthreads();
    }
    const int excl = s[t] - pair + bsum[b];
    if (i0 < N_NODES)     { offsets[i0]     = excl;      cursor[i0]     = excl; }
    if (i0 + 1 < N_NODES) { offsets[i0 + 1] = excl + c0; cursor[i0 + 1] = excl + c0; }
}

__global__ void place_kernel(const int* __restrict__ edges,
                             int* __restrict__ cursor,
                             int* __restrict__ edge_ids) {
    const int stride = gridDim.x * blockDim.x;
    const int2* e2 = (const int2*)edges;
    for (int e = blockIdx.x * blockDim.x + threadIdx.x; e < N_EDGES; e += stride) {
        const int src = e2[e].x;
        const int pos = atomicAdd(&cursor[src], 1);
        edge_ids[pos] = e;
    }
}

// One wave per node; lane = class. 4-way software pipeline over the node's
// contiguous edge list (4 independent 256B row loads in flight per wave).
__global__ __launch_bounds__(256) void gather_kernel(
        const int* __restrict__ offsets,
        const int* __restrict__ edge_ids,
        const float* __restrict__ weights,
        const float* __restrict__ poss_edge,
        const float* __restrict__ nsum,
        float* __restrict__ acc,
        float* __restrict__ pe_out) {
    const int gtid = blockIdx.x * blockDim.x + threadIdx.x;
    const int node = gtid >> 6;
    const int lane = threadIdx.x & 63;
    if (node >= N_NODES) return;

    const int beg = offsets[node];
    const int end = offsets[node + 1];
    const int n   = end - beg;
    const int* ids = edge_ids + beg;

    float val = 0.0f;
    int j = 0;
    for (; j + 4 <= n; j += 4) {
        const int e0 = ids[j], e1 = ids[j + 1], e2 = ids[j + 2], e3 = ids[j + 3];
        const float w0 = weights[e0], w1 = weights[e1], w2 = weights[e2], w3 = weights[e3];
        const size_t r0 = (size_t)e0 * N_CLASS + lane;
        const size_t r1 = (size_t)e1 * N_CLASS + lane;
        const size_t r2 = (size_t)e2 * N_CLASS + lane;
        const size_t r3 = (size_t)e3 * N_CLASS + lane;
        const float a0 = __builtin_nontemporal_load(poss_edge + r0);
        const float a1 = __builtin_nontemporal_load(poss_edge + r1);
        const float a2 = __builtin_nontemporal_load(poss_edge + r2);
        const float a3 = __builtin_nontemporal_load(poss_edge + r3);
        __builtin_nontemporal_store(a0, pe_out + r0);
        __builtin_nontemporal_store(a1, pe_out + r1);
        __builtin_nontemporal_store(a2, pe_out + r2);
        __builtin_nontemporal_store(a3, pe_out + r3);
        val = fmaf(a0, w0, val);
        val = fmaf(a1, w1, val);
        val = fmaf(a2, w2, val);
        val = fmaf(a3, w3, val);
    }
    for (; j < n; ++j) {
        const int e = ids[j];
        const size_t r = (size_t)e * N_CLASS + lane;
        const float a = __builtin_nontemporal_load(poss_edge + r);
        __builtin_nontemporal_store(a, pe_out + r);
        val = fmaf(a, weights[e], val);
    }
    acc[(size_t)node * N_CLASS + lane] = val / nsum[node];
}

// ---------------- fallback (atomic path, used only if ws too small) ----------------
__global__ void scatter_copy_kernel(const int* __restrict__ edges,
                                    const float* __restrict__ weights,
                                    const float* __restrict__ poss_edge,
                                    float* __restrict__ acc,
                                    float* __restrict__ pe_out) {
    const int total = N_EDGES * 16;
    const int stride = gridDim.x * blockDim.x;
    for (int t = blockIdx.x * blockDim.x + threadIdx.x; t < total; t += stride) {
        const int e  = t >> 4;
        const int c0 = (t & 15) << 2;
        const float4 pe = *reinterpret_cast<const float4*>(poss_edge + (size_t)e * N_CLASS + c0);
        const float  w  = weights[e];
        const int    src = edges[2 * e];
        *reinterpret_cast<float4*>(pe_out + (size_t)e * N_CLASS + c0) = pe;
        float* a = acc + (size_t)src * N_CLASS + c0;
        atomicAdd(a + 0, pe.x * w);
        atomicAdd(a + 1, pe.y * w);
        atomicAdd(a + 2, pe.z * w);
        atomicAdd(a + 3, pe.w * w);
    }
}

__global__ void divide_kernel(float* __restrict__ acc,
                              const float* __restrict__ nsum) {
    const int t = blockIdx.x * blockDim.x + threadIdx.x;
    if (t >= N_NODES * 16) return;
    const int   node = t >> 4;
    const float d    = nsum[node];
    float4 v = *reinterpret_cast<float4*>(acc + (size_t)t * 4);
    v.x /= d; v.y /= d; v.z /= d; v.w /= d;
    *reinterpret_cast<float4*>(acc + (size_t)t * 4) = v;
}

extern "C" void kernel_launch(void* const* d_in, const int* in_sizes, int n_in,
                              void* d_out, int out_size, void* d_ws, size_t ws_size,
                              hipStream_t stream) {
    const int*   edges     = (const int*)d_in[0];
    const float* weights   = (const float*)d_in[1];
    const float* poss_edge = (const float*)d_in[2];
    const float* nsum      = (const float*)d_in[3];

    float* out    = (float*)d_out;
    float* acc    = out;                                  // N_NODES*64 floats
    float* pe_out = out + (size_t)N_NODES * N_CLASS;

    const size_t ws_needed =
        (size_t)(N_NODES + 1 + N_NODES + 256 + N_EDGES) * sizeof(int);   // ~7.2 MB

    if (ws_size >= ws_needed) {
        int* offsets  = (int*)d_ws;                       // N_NODES+1 (counts first)
        int* cursor   = offsets + (N_NODES + 1);          // N_NODES
        int* bsum     = cursor + N_NODES;                 // 256
        int* edge_ids = bsum + 256;                       // N_EDGES

        hipMemsetAsync(offsets, 0, (size_t)N_NODES * sizeof(int), stream);
        hist_kernel <<<2048, 256, 0, stream>>>(edges, offsets);
        scanA_kernel<<<SCAN_NB, SCAN_T, 0, stream>>>(offsets, bsum);
        scanB_kernel<<<1, SCAN_T, 0, stream>>>(bsum, offsets);
        scanC_kernel<<<SCAN_NB, SCAN_T, 0, stream>>>(offsets, bsum, cursor);
        place_kernel<<<2048, 256, 0, stream>>>(edges, cursor, edge_ids);

        const int threads = N_NODES * 64;                 // one wave per node
        gather_kernel<<<(threads + 255) / 256, 256, 0, stream>>>(
            offsets, edge_ids, weights, poss_edge, nsum, acc, pe_out);
    } else {
        hipMemsetAsync(acc, 0, (size_t)N_NODES * N_CLASS * sizeof(float), stream);
        scatter_copy_kernel<<<8192, 256, 0, stream>>>(edges, weights, poss_edge, acc, pe_out);
        const int div_threads = N_NODES * 16;
        divide_kernel<<<(div_threads + 255) / 256, 256, 0, stream>>>(acc, nsum);
    }
}

// Round 5
// 388.225 us; speedup vs baseline: 3.5798x; 1.0297x over previous
//
#include <hip/hip_runtime.h>

#define N_NODES 100000
#define N_CLASS 64          // NUM_CLASS + 1
#define N_EDGES 1600000
#define SCAN_NB 200         // 200 blocks * 512 elems = 102400 >= N_NODES
#define SCAN_T  256

typedef float f4 __attribute__((ext_vector_type(4)));   // native vector type
                                                        // (works with __builtin_nontemporal_*)

// ws layout: offsets [N_NODES+1] | cursor [N_NODES] | bsum [256] | edge_ids [N_EDGES]
// hist accumulates counts directly into offsets[0..N-1]; scan converts in-place.

__global__ void hist_kernel(const int* __restrict__ edges, int* __restrict__ counts) {
    const int stride = gridDim.x * blockDim.x;
    const int2* e2 = (const int2*)edges;
    for (int e = blockIdx.x * blockDim.x + threadIdx.x; e < N_EDGES; e += stride) {
        atomicAdd(&counts[e2[e].x], 1);
    }
}

// Phase A: per-block sums of 512-count tiles
__global__ void scanA_kernel(const int* __restrict__ counts, int* __restrict__ bsum) {
    __shared__ int s[SCAN_T];
    const int b = blockIdx.x, t = threadIdx.x;
    const int i0 = b * 512 + 2 * t;
    int c0 = (i0     < N_NODES) ? counts[i0]     : 0;
    int c1 = (i0 + 1 < N_NODES) ? counts[i0 + 1] : 0;
    s[t] = c0 + c1;
    __syncthreads();
    for (int d = SCAN_T / 2; d > 0; d >>= 1) {
        if (t < d) s[t] += s[t + d];
        __syncthreads();
    }
    if (t == 0) bsum[b] = s[0];
}

// Phase B: exclusive scan of the 200 block sums (single tiny block)
__global__ void scanB_kernel(int* __restrict__ bsum, int* __restrict__ offsets) {
    __shared__ int s[SCAN_T];
    const int t = threadIdx.x;
    const int v = (t < SCAN_NB) ? bsum[t] : 0;
    s[t] = v;
    __syncthreads();
    for (int d = 1; d < SCAN_T; d <<= 1) {
        int x = (t >= d) ? s[t - d] : 0;
        __syncthreads();
        s[t] += x;
        __syncthreads();
    }
    if (t < SCAN_NB) bsum[t] = s[t] - v;              // exclusive
    if (t == SCAN_T - 1) offsets[N_NODES] = s[t];     // total = N_EDGES
}

// Phase C: local exclusive scan per tile + block offset; writes offsets & cursor.
__global__ void scanC_kernel(int* __restrict__ offsets, const int* __restrict__ bsum,
                             int* __restrict__ cursor) {
    __shared__ int s[SCAN_T];
    const int b = blockIdx.x, t = threadIdx.x;
    const int i0 = b * 512 + 2 * t;
    int c0 = (i0     < N_NODES) ? offsets[i0]     : 0;
    int c1 = (i0 + 1 < N_NODES) ? offsets[i0 + 1] : 0;
    const int pair = c0 + c1;
    s[t] = pair;
    __syncthreads();
    for (int d = 1; d < SCAN_T; d <<= 1) {
        int x = (t >= d) ? s[t - d] : 0;
        __syncthreads();
        s[t] += x;
        __syncthreads();
    }
    const int excl = s[t] - pair + bsum[b];
    if (i0 < N_NODES)     { offsets[i0]     = excl;      cursor[i0]     = excl; }
    if (i0 + 1 < N_NODES) { offsets[i0 + 1] = excl + c0; cursor[i0 + 1] = excl + c0; }
}

__global__ void place_kernel(const int* __restrict__ edges,
                             int* __restrict__ cursor,
                             int* __restrict__ edge_ids) {
    const int stride = gridDim.x * blockDim.x;
    const int2* e2 = (const int2*)edges;
    for (int e = blockIdx.x * blockDim.x + threadIdx.x; e < N_EDGES; e += stride) {
        const int src = e2[e].x;
        const int pos = atomicAdd(&cursor[src], 1);
        edge_ids[pos] = e;
    }
}

// One wave per node. Lane layout: grp = lane>>4 selects one of 4 edges,
// q = lane&15 selects a float4 class-quad. One VMEM instruction moves
// 4 full 256B edge rows (1KB). 8-edge main step = 2KB in flight per wave.
// Finish: shfl_xor(16), shfl_xor(32) folds the 4 edge-groups; group 0
// writes the node's 256B output row.
__global__ __launch_bounds__(256) void gather_kernel(
        const int* __restrict__ offsets,
        const int* __restrict__ edge_ids,
        const float* __restrict__ weights,
        const float* __restrict__ poss_edge,
        const float* __restrict__ nsum,
        float* __restrict__ acc,
        float* __restrict__ pe_out) {
    const int node = blockIdx.x * 4 + (threadIdx.x >> 6);
    const int lane = threadIdx.x & 63;
    const int grp  = lane >> 4;          // edge slot 0..3
    const int q    = lane & 15;          // class quad 0..15
    if (node >= N_NODES) return;

    const int beg = offsets[node];
    const int n   = offsets[node + 1] - beg;
    const int* ids = edge_ids + beg;

    f4 val = (f4)(0.0f);
    int j = 0;

    // main: 8 edges per iteration (2 x 4-edge groups)
    for (; j + 8 <= n; j += 8) {
        const int e0 = ids[j + grp];
        const int e1 = ids[j + 4 + grp];
        const float w0 = weights[e0];
        const float w1 = weights[e1];
        const size_t r0 = (size_t)e0 * N_CLASS + q * 4;
        const size_t r1 = (size_t)e1 * N_CLASS + q * 4;
        const f4 a0 = __builtin_nontemporal_load((const f4*)(poss_edge + r0));
        const f4 a1 = __builtin_nontemporal_load((const f4*)(poss_edge + r1));
        __builtin_nontemporal_store(a0, (f4*)(pe_out + r0));
        __builtin_nontemporal_store(a1, (f4*)(pe_out + r1));
        val += a0 * w0;
        val += a1 * w1;
    }
    // remainder: up to 4 edges per iteration, masked by group
    for (; j < n; j += 4) {
        if (grp < n - j) {
            const int e = ids[j + grp];
            const float w = weights[e];
            const size_t r = (size_t)e * N_CLASS + q * 4;
            const f4 a = __builtin_nontemporal_load((const f4*)(poss_edge + r));
            __builtin_nontemporal_store(a, (f4*)(pe_out + r));
            val += a * w;
        }
    }

    // fold 4 edge-groups (lanes differing in bits 4,5)
    val.x += __shfl_xor(val.x, 16); val.y += __shfl_xor(val.y, 16);
    val.z += __shfl_xor(val.z, 16); val.w += __shfl_xor(val.w, 16);
    val.x += __shfl_xor(val.x, 32); val.y += __shfl_xor(val.y, 32);
    val.z += __shfl_xor(val.z, 32); val.w += __shfl_xor(val.w, 32);

    if (grp == 0) {
        const float inv = 1.0f / nsum[node];
        f4 o = val * inv;
        *reinterpret_cast<f4*>(acc + (size_t)node * N_CLASS + q * 4) = o;
    }
}

// ---------------- fallback (atomic path, used only if ws too small) ----------------
__global__ void scatter_copy_kernel(const int* __restrict__ edges,
                                    const float* __restrict__ weights,
                                    const float* __restrict__ poss_edge,
                                    float* __restrict__ acc,
                                    float* __restrict__ pe_out) {
    const int total = N_EDGES * 16;
    const int stride = gridDim.x * blockDim.x;
    for (int t = blockIdx.x * blockDim.x + threadIdx.x; t < total; t += stride) {
        const int e  = t >> 4;
        const int c0 = (t & 15) << 2;
        const float4 pe = *reinterpret_cast<const float4*>(poss_edge + (size_t)e * N_CLASS + c0);
        const float  w  = weights[e];
        const int    src = edges[2 * e];
        *reinterpret_cast<float4*>(pe_out + (size_t)e * N_CLASS + c0) = pe;
        float* a = acc + (size_t)src * N_CLASS + c0;
        atomicAdd(a + 0, pe.x * w);
        atomicAdd(a + 1, pe.y * w);
        atomicAdd(a + 2, pe.z * w);
        atomicAdd(a + 3, pe.w * w);
    }
}

__global__ void divide_kernel(float* __restrict__ acc,
                              const float* __restrict__ nsum) {
    const int t = blockIdx.x * blockDim.x + threadIdx.x;
    if (t >= N_NODES * 16) return;
    const int   node = t >> 4;
    const float d    = nsum[node];
    float4 v = *reinterpret_cast<float4*>(acc + (size_t)t * 4);
    v.x /= d; v.y /= d; v.z /= d; v.w /= d;
    *reinterpret_cast<float4*>(acc + (size_t)t * 4) = v;
}

extern "C" void kernel_launch(void* const* d_in, const int* in_sizes, int n_in,
                              void* d_out, int out_size, void* d_ws, size_t ws_size,
                              hipStream_t stream) {
    const int*   edges     = (const int*)d_in[0];
    const float* weights   = (const float*)d_in[1];
    const float* poss_edge = (const float*)d_in[2];
    const float* nsum      = (const float*)d_in[3];

    float* out    = (float*)d_out;
    float* acc    = out;                                  // N_NODES*64 floats
    float* pe_out = out + (size_t)N_NODES * N_CLASS;

    const size_t ws_needed =
        (size_t)(N_NODES + 1 + N_NODES + 256 + N_EDGES) * sizeof(int);   // ~7.2 MB

    if (ws_size >= ws_needed) {
        int* offsets  = (int*)d_ws;                       // N_NODES+1 (counts first)
        int* cursor   = offsets + (N_NODES + 1);          // N_NODES
        int* bsum     = cursor + N_NODES;                 // 256
        int* edge_ids = bsum + 256;                       // N_EDGES

        (void)hipMemsetAsync(offsets, 0, (size_t)N_NODES * sizeof(int), stream);
        hist_kernel <<<2048, 256, 0, stream>>>(edges, offsets);
        scanA_kernel<<<SCAN_NB, SCAN_T, 0, stream>>>(offsets, bsum);
        scanB_kernel<<<1, SCAN_T, 0, stream>>>(bsum, offsets);
        scanC_kernel<<<SCAN_NB, SCAN_T, 0, stream>>>(offsets, bsum, cursor);
        place_kernel<<<2048, 256, 0, stream>>>(edges, cursor, edge_ids);

        gather_kernel<<<(N_NODES + 3) / 4, 256, 0, stream>>>(
            offsets, edge_ids, weights, poss_edge, nsum, acc, pe_out);
    } else {
        (void)hipMemsetAsync(acc, 0, (size_t)N_NODES * N_CLASS * sizeof(float), stream);
        scatter_copy_kernel<<<8192, 256, 0, stream>>>(edges, weights, poss_edge, acc, pe_out);
        const int div_threads = N_NODES * 16;
        divide_kernel<<<(div_threads + 255) / 256, 256, 0, stream>>>(acc, nsum);
    }
}